// Round 6
// baseline (776.316 us; speedup 1.0000x reference)
//
#include <hip/hip_runtime.h>

// z_{t+1} = z_t @ K, T=256, B=256, D=512. out[b,t,d] = (z0 @ K^{t+1})[b,d], fp32.
//
// ONE persistent-block kernel with a ticket-ordered job queue + per-stage done
// counters (device-scope flags). Removes the ~130us of kernel-boundary cost
// (10 dispatches x ~12us) that dominated the 240us multi-kernel version, and
// lets out-jobs with early-ready inputs run on CUs idle during small ladder
// stages. grid.sync fusion measured 2.3x worse (R2); stage-boundary piggyback
// measured worse (R3); z-major swizzle neutral (R4).
//
// Liveness: blocks acquire tickets IN ORDER; every range depends only on
// strictly earlier ranges; so the smallest in-flight job is always runnable
// -> deadlock-free for any dispatch order / residency (even 1 block).
// Coherence: producer = __syncthreads (vmcnt0 drain) + __threadfence +
// agent-scope atomicAdd; consumer = relaxed agent-scope spin + __threadfence.
// Same primitive as cg::grid.sync, which passed correctness in R2.
//
// Algorithm unchanged: chunked matrix powers c=16 (depth-8 ladder, bf16x3
// split), U_j = z0 @ K^{16j} by doubling batched into squaring stages, then
// out[16j+i-1] = U_j @ K^i (plain bf16). Job bodies byte-identical to R2/R1.
//
// ALL intermediates fragment-packed: 1KB chunks = exactly what 64 lanes of one
// 16x16x32 MFMA fragment read (elem = chunk*512 + lane*8 + j). A-operands load
// straight from global; B panels CONTIGUOUS -> staged as consecutive 1KB
// gll16's, ONE barrier per K-loop. Slot layout: [Apk-hi|Apk-lo|Bpk-hi|Bpk-lo].

typedef unsigned short u16;
typedef unsigned int u32;
typedef __bf16 bf16x8 __attribute__((ext_vector_type(8)));
typedef float f32x4 __attribute__((ext_vector_type(4)));
typedef u16 u16x4 __attribute__((ext_vector_type(4)));
typedef u16 u16x8 __attribute__((ext_vector_type(8)));

#define MAT 262144    /* 512*512 elems */
#define SLOT 1048576  /* 4*MAT u16 per power slot */
#define WSLOT 131072  /* 256*512 */
#define NJOBS 5392

__device__ __forceinline__ u16 f2b(float f) {  // fp32 -> bf16 (RNE)
  u32 x = __float_as_uint(f);
  return (u16)((x + 0x7fffu + ((x >> 16) & 1u)) >> 16);
}
__device__ __forceinline__ float b2f(u16 u) { return __uint_as_float(((u32)u) << 16); }

// fragment-packed index for element (r, k), K-dim = 512
__device__ __forceinline__ size_t pidx(int r, int k) {
  return (size_t)(((r >> 4) * 16 + (k >> 5)) * 512 + ((k >> 3) & 3) * 128 + (r & 15) * 8 + (k & 7));
}

__device__ __forceinline__ void gll16(const void* g, void* l) {
  __builtin_amdgcn_global_load_lds((__attribute__((address_space(1))) void*)(void*)g,
                                   (__attribute__((address_space(3))) void*)l, 16, 0, 0);
}

// ---- prep job b in [0,80): pack K into slot0 (4 forms); split z0 -> U_0 hi/lo ----
__device__ void prep_job(int b, int tid, const float* __restrict__ Kc,
                         const float* __restrict__ z0, u16* __restrict__ P,
                         u16* __restrict__ Uh, u16* __restrict__ Ul) {
  if (b < 64) {
    int r0 = (b >> 3) * 64, c0b = (b & 7) * 64;
#pragma unroll
    for (int q = 0; q < 2; ++q) {
      int g = q * 256 + tid;            // 512 groups: 64 rows x 8 col-groups
      int r = r0 + (g >> 3), c0 = c0b + (g & 7) * 8;
      float4 v0 = *(const float4*)(Kc + (size_t)r * 512 + c0);
      float4 v1 = *(const float4*)(Kc + (size_t)r * 512 + c0 + 4);
      float v[8] = {v0.x, v0.y, v0.z, v0.w, v1.x, v1.y, v1.z, v1.w};
      u16x8 h8, l8v;
#pragma unroll
      for (int j = 0; j < 8; ++j) {
        u16 h = f2b(v[j]);
        h8[j] = h;
        l8v[j] = f2b(v[j] - b2f(h));
        size_t ib = pidx(c0 + j, r);    // transposed form, scalar
        P[2 * MAT + ib] = h;
        P[3 * MAT + ib] = l8v[j];
      }
      size_t ia = pidx(r, c0);          // row form, contiguous 8 -> 16B stores
      *(u16x8*)(P + ia) = h8;
      *(u16x8*)(P + MAT + ia) = l8v;
    }
  } else {
    int idb = b - 64;  // 16 jobs x 4 iters x 256 threads x 8 elems = 131072
#pragma unroll
    for (int q = 0; q < 4; ++q) {
      int g = (idb * 4 + q) * 256 + tid;
      int r = g >> 6, c0 = (g & 63) * 8;
      float4 v0 = *(const float4*)(z0 + (size_t)r * 512 + c0);
      float4 v1 = *(const float4*)(z0 + (size_t)r * 512 + c0 + 4);
      float v[8] = {v0.x, v0.y, v0.z, v0.w, v1.x, v1.y, v1.z, v1.w};
      u16x8 h8, l8v;
#pragma unroll
      for (int j = 0; j < 8; ++j) {
        u16 h = f2b(v[j]);
        h8[j] = h;
        l8v[j] = f2b(v[j] - b2f(h));
      }
      size_t ia = pidx(r, c0);
      *(u16x8*)(Uh + ia) = h8;
      *(u16x8*)(Ul + ia) = l8v;
    }
  }
}

// ladder stage parameters (P slots: 0..15 = K^1..16; 16 = K^32; 17 = K^64; 18 = K^128)
struct LP { int asl, astrf, csl, cstrf, bsl, nfull, rm, tm, uoff, ny; };
__device__ const LP g_lp[8] = {
    {0, 0, 1, 0, 0, 1, 0x1, 0x1, 0, 8},      // s1: K^2
    {0, 1, 2, 1, 1, 1, 0x3, 0x2, 0, 8},      // s2: K^3,K^4
    {0, 1, 4, 1, 3, 1, 0xF, 0x8, 0, 8},      // s3: K^5..8
    {0, 1, 8, 1, 7, 1, 0x80, 0x80, 0, 8},    // s4: K^9..16
    {15, 0, 16, 0, 15, 1, 0x1, 0x1, 1, 12},  // s5: K^32 + U_1
    {16, 0, 17, 0, 16, 1, 0x1, 0x1, 2, 16},  // s6: K^64 + U_{2,3}
    {17, 0, 18, 0, 17, 1, 0x0, 0x1, 4, 24},  // s7: K^128 + U_{4..7}
    {18, 0, 18, 0, 18, 0, 0x0, 0x0, 8, 32},  // s8: U_{8..15}
};

// ---- ladder job: one shared B panel (hi+lo, 64KB LDS, ONE barrier). bf16x3.
__device__ void stage_job(u16* Bs, int tid, int x, int y, int z, const LP& p,
                          u16* __restrict__ P, u16* __restrict__ Uh,
                          u16* __restrict__ Ul) {
  const u16* fA = P + (size_t)p.asl * SLOT;
  u16* fC = P + (size_t)p.csl * SLOT;
  const u16* Bh = P + (size_t)p.bsl * SLOT + 2 * MAT;
  const u16 *Ah, *Al;
  u16 *Ch, *Clo, *CTh, *CTl;
  int m0;
  bool full = (y < 8 * p.nfull);
  bool wrow, wtlo;
  if (full) {
    Ah = fA + (size_t)z * (p.astrf ? SLOT : 0);
    Al = Ah + MAT;
    Ch = fC + (size_t)z * (p.cstrf ? SLOT : 0);
    Clo = Ch + MAT;
    CTh = Ch + 2 * MAT;
    CTl = Ch + 3 * MAT;
    m0 = y * 64;
    wrow = (p.rm >> z) & 1;
    wtlo = (p.tm >> z) & 1;
  } else {
    int yy = y - 8 * p.nfull;
    int u = yy >> 2;
    Ah = Uh + (size_t)u * WSLOT;
    Al = Ah + 16 * (size_t)WSLOT;
    Ch = Uh + (size_t)(p.uoff + u) * WSLOT;
    Clo = Ch + 16 * (size_t)WSLOT;
    CTh = CTl = nullptr;
    m0 = (yy & 3) * 64;
    wrow = true;
    wtlo = false;
  }
  const u16* Bl = Bh + MAT;
  int n0 = x * 32;
  int wv = tid >> 6, lane = tid & 63;
  int mrow = lane & 15, quad = lane >> 4;
  int l8 = lane * 8;
  int nchunk0 = n0 >> 4;                 // 2 nchunks x 16 kchunks = 32 chunks/form
  const u16* ph = Bh + (size_t)nchunk0 * 16 * 512;  // contiguous 32KB panel
  const u16* pl = Bl + (size_t)nchunk0 * 16 * 512;
#pragma unroll
  for (int i = 0; i < 8; ++i) {          // wave wv stages chunks wv*8+i (hi & lo)
    int ch = wv * 8 + i;
    gll16(ph + (size_t)ch * 512 + l8, Bs + ch * 512);
    gll16(pl + (size_t)ch * 512 + l8, Bs + 16384 + ch * 512);
  }
  __syncthreads();                       // the ONLY barrier in the K-loop
  int mc = (m0 >> 4) + wv;               // wave-tile 16x32 (4-way m-split)
  f32x4 acc[2] = {};
#pragma unroll 4
  for (int kt = 0; kt < 16; ++kt) {
    size_t co = (size_t)(mc * 16 + kt) * 512 + l8;
    bf16x8 ah = *(const bf16x8*)(Ah + co);
    bf16x8 al = *(const bf16x8*)(Al + co);
#pragma unroll
    for (int nt = 0; nt < 2; ++nt) {
      bf16x8 bh = *(const bf16x8*)(Bs + (nt * 16 + kt) * 512 + l8);
      bf16x8 bl = *(const bf16x8*)(Bs + 16384 + (nt * 16 + kt) * 512 + l8);
      acc[nt] = __builtin_amdgcn_mfma_f32_16x16x32_bf16(ah, bh, acc[nt], 0, 0, 0);
      acc[nt] = __builtin_amdgcn_mfma_f32_16x16x32_bf16(al, bh, acc[nt], 0, 0, 0);
      acc[nt] = __builtin_amdgcn_mfma_f32_16x16x32_bf16(ah, bl, acc[nt], 0, 0, 0);
    }
  }
  // C/D layout: col = lane&15, row = quad*4 + reg
  int mbase = m0 + wv * 16 + quad * 4;
#pragma unroll
  for (int nt = 0; nt < 2; ++nt) {
    int n = n0 + nt * 16 + mrow;
    u16x4 h4, l4;
#pragma unroll
    for (int r = 0; r < 4; ++r) {
      float v = acc[nt][r];
      u16 h = f2b(v);
      h4[r] = h;
      l4[r] = f2b(v - b2f(h));
    }
    if (wrow) {
#pragma unroll
      for (int r = 0; r < 4; ++r) {
        size_t ia = pidx(mbase + r, n);
        Ch[ia] = h4[r];
        Clo[ia] = l4[r];
      }
    }
    if (full) {
      size_t ib = pidx(n, mbase);        // 4 consecutive u16 (m&7 = quad&1*4 + r)
      *(u16x4*)(CTh + ib) = h4;
      if (wtlo) *(u16x4*)(CTl + ib) = l4;
    }
  }
}

// ---- out job: out[:, zo, :] = U_{zo>>4} @ K^{(zo&15)+1}, plain bf16.
// 256x64 tile, whole-K 64KB panel staged once, ONE barrier, 4-way m-split.
__device__ void out_job(u16* Bs, int tid, int x, int zo,
                        const u16* __restrict__ Ub, const u16* __restrict__ PT0,
                        float* __restrict__ out) {
  const u16* A = Ub + (size_t)(zo >> 4) * WSLOT;
  const u16* Bt = PT0 + (size_t)(zo & 15) * SLOT;
  int n0 = x * 64;
  int wv = tid >> 6, lane = tid & 63;
  int mrow = lane & 15, quad = lane >> 4;
  int l8 = lane * 8;
  const u16* pb = Bt + (size_t)(n0 >> 4) * 16 * 512;  // contiguous 64KB panel
#pragma unroll
  for (int i = 0; i < 16; ++i) {
    int ch = wv * 16 + i;
    gll16(pb + (size_t)ch * 512 + l8, Bs + ch * 512);
  }
  __syncthreads();
  int mc0 = wv * 4;                      // wave-tile 64x64
  f32x4 acc[4][4] = {};
#pragma unroll 4
  for (int kt = 0; kt < 16; ++kt) {
    bf16x8 a[4], b[4];
#pragma unroll
    for (int mt = 0; mt < 4; ++mt)
      a[mt] = *(const bf16x8*)(A + (size_t)((mc0 + mt) * 16 + kt) * 512 + l8);
#pragma unroll
    for (int nt = 0; nt < 4; ++nt)
      b[nt] = *(const bf16x8*)(Bs + (nt * 16 + kt) * 512 + l8);
#pragma unroll
    for (int mt = 0; mt < 4; ++mt)
#pragma unroll
      for (int nt = 0; nt < 4; ++nt)
        acc[mt][nt] = __builtin_amdgcn_mfma_f32_16x16x32_bf16(a[mt], b[nt], acc[mt][nt], 0, 0, 0);
  }
#pragma unroll
  for (int mt = 0; mt < 4; ++mt)
#pragma unroll
    for (int nt = 0; nt < 4; ++nt) {
      int gb = wv * 64 + mt * 16 + quad * 4;
      int gd = n0 + nt * 16 + mrow;
#pragma unroll
      for (int r = 0; r < 4; ++r)
        out[((size_t)(gb + r) * 256 + zo) * 512 + gd] = acc[mt][nt][r];
    }
}

// ---- job ranges in ticket order. kind: 0=prep, 1=ladder (prm=stage),
// 2=out (prm=zbase). dep/sig index stage counters ctrl[1+i]:
// 0=prep(80) 1=s1(128) 2=s2(256) 3=s3(512) 4=s4(1024) 5=s5(192) 6=s6(256)
// 7=s7(384) 8=s8(512). Every range depends only on earlier ranges -> live.
struct RG { int start, kind, prm, dep, need, sig; };
__device__ const RG g_rg[18] = {
    {0,    0, 0,  -1, 0,    0},   // prep
    {80,   1, 0,   0, 80,   1},   // s1
    {208,  2, 0,   0, 80,  -1},   // out z=0
    {216,  1, 1,   1, 128,  2},   // s2
    {472,  2, 1,   1, 128, -1},   // out z=1
    {480,  1, 2,   2, 256,  3},   // s3
    {992,  2, 2,   2, 256, -1},   // out z=2..3
    {1008, 1, 3,   3, 512,  4},   // s4
    {2032, 2, 4,   3, 512, -1},   // out z=4..7
    {2064, 1, 4,   4, 1024, 5},   // s5
    {2256, 2, 8,   4, 1024,-1},   // out z=8..15
    {2320, 1, 5,   5, 192,  6},   // s6
    {2576, 2, 16,  5, 192, -1},   // out z=16..31
    {2704, 1, 6,   6, 256,  7},   // s7
    {3088, 2, 32,  6, 256, -1},   // out z=32..63
    {3344, 1, 7,   7, 384,  8},   // s8
    {3856, 2, 64,  7, 384, -1},   // out z=64..127
    {4368, 2, 128, 8, 512, -1},   // out z=128..255
};

__global__ __launch_bounds__(256, 2) void mega(const float* Kc, const float* z0,
                                               u16* P, u16* Uh, u16* Ul,
                                               float* out, u32* ctrl) {
  __shared__ u16 Bs[32768];  // 64KB
  __shared__ int sh_t;
  int tid = threadIdx.x;
  for (;;) {
    __syncthreads();                     // all threads done with prior job/sh_t
    if (tid == 0) sh_t = (int)atomicAdd(ctrl, 1u);
    __syncthreads();
    int t = sh_t;
    if (t >= NJOBS) return;
    int ri = 0;
#pragma unroll
    for (int i = 1; i < 18; ++i)
      if (t >= g_rg[i].start) ri = i;
    RG rg = g_rg[ri];
    if (rg.dep >= 0) {
      if (tid == 0) {
        u32* c = ctrl + 1 + rg.dep;
        while ((int)__hip_atomic_load(c, __ATOMIC_RELAXED, __HIP_MEMORY_SCOPE_AGENT) < rg.need)
          __builtin_amdgcn_s_sleep(8);
        __threadfence();                 // acquire: invalidate stale caches
      }
      __syncthreads();
    }
    int e = t - rg.start;
    if (rg.kind == 0) {
      prep_job(e, tid, Kc, z0, P, Uh, Ul);
    } else if (rg.kind == 1) {
      LP p = g_lp[rg.prm];
      int x = e & 15, q = e >> 4;
      stage_job(Bs, tid, x, q % p.ny, q / p.ny, p, P, Uh, Ul);
    } else {
      out_job(Bs, tid, e & 7, rg.prm + (e >> 3), Uh, P + 2 * MAT, out);
    }
    __syncthreads();                     // drain block's stores (vmcnt 0)
    if (rg.sig >= 0 && tid == 0) {
      __threadfence();                   // release: writeback before signal
      __hip_atomic_fetch_add(ctrl + 1 + rg.sig, 1u, __ATOMIC_RELAXED,
                             __HIP_MEMORY_SCOPE_AGENT);
    }
  }
}

extern "C" void kernel_launch(void* const* d_in, const int* in_sizes, int n_in,
                              void* d_out, int out_size, void* d_ws, size_t ws_size,
                              hipStream_t stream) {
  const float* z0 = (const float*)d_in[0];
  const float* Kc = (const float*)d_in[1];
  float* out = (float*)d_out;
  // ws layout (u16): Uh[16*WSLOT] | Ul[16*WSLOT] | P[19*SLOT]
  // P slots: 0..15 = K^1..K^16; 16 = K^32; 17 = K^64; 18 = K^128
  u16* Uh = (u16*)d_ws;
  u16* Ul = Uh + 16 * (size_t)WSLOT;
  u16* P = Ul + 16 * (size_t)WSLOT;
  // control block (ticket + 9 stage counters) lives in a DEAD hole: slot 8's
  // row-hi form (K^9 rows) is never written (rowmask 0x80 gates z=0) nor read.
  u32* ctrl = (u32*)(P + 8 * (size_t)SLOT);

  hipMemsetAsync(ctrl, 0, 64, stream);
  mega<<<dim3(512), dim3(256), 0, stream>>>(Kc, z0, P, Uh, Ul, out, ctrl);
}

// Round 7
// 668.219 us; speedup vs baseline: 1.1618x; 1.1618x over previous
//
#include <hip/hip_runtime.h>

// z_{t+1} = z_t @ K, T=256, B=256, D=512. out[b,t,d] = (z0 @ K^{t+1})[b,d], fp32.
//
// ONE persistent-block kernel, ticket-ordered job queue + per-stage done
// counters. R6 measured 683us with MfmaUtil 3.2% == R2 coop-fusion's 673us:
// shared pathology = ALL control words on ONE cacheline (ticket atomicAdds +
// stage signals invalidating the line ~450 blocks spin on, cross-XCD).
// R7 fix: (1) each counter on its own 128B line; (2) spin backoff s_sleep(16).
// Job bodies / ranges / fences byte-identical to R6 (which passed refcheck).
//
// Liveness: blocks acquire tickets IN ORDER; every range depends only on
// strictly earlier ranges; so the smallest in-flight job is always runnable
// -> deadlock-free for any dispatch order / residency (even 1 block).
// Coherence: producer = __syncthreads (vmcnt0 drain) + __threadfence +
// agent-scope atomicAdd; consumer = relaxed agent-scope spin + __threadfence.
//
// Algorithm: chunked matrix powers c=16 (depth-8 ladder = log2(256),
// irreducible), bf16x3 split. U_j = z0 @ K^{16j} by doubling batched into
// squaring stages, then out[16j+i-1] = U_j @ K^i (plain bf16).
//
// ALL intermediates fragment-packed: 1KB chunks = exactly what 64 lanes of one
// 16x16x32 MFMA fragment read (elem = chunk*512 + lane*8 + j). A-operands load
// straight from global; B panels CONTIGUOUS -> staged as consecutive 1KB
// gll16's, ONE barrier per K-loop. Slot layout: [Apk-hi|Apk-lo|Bpk-hi|Bpk-lo].

typedef unsigned short u16;
typedef unsigned int u32;
typedef __bf16 bf16x8 __attribute__((ext_vector_type(8)));
typedef float f32x4 __attribute__((ext_vector_type(4)));
typedef u16 u16x4 __attribute__((ext_vector_type(4)));
typedef u16 u16x8 __attribute__((ext_vector_type(8)));

#define MAT 262144    /* 512*512 elems */
#define SLOT 1048576  /* 4*MAT u16 per power slot */
#define WSLOT 131072  /* 256*512 */
#define NJOBS 5392
#define CPAD 32       /* u32 per control slot = 128B -> one cacheline each */

__device__ __forceinline__ u16 f2b(float f) {  // fp32 -> bf16 (RNE)
  u32 x = __float_as_uint(f);
  return (u16)((x + 0x7fffu + ((x >> 16) & 1u)) >> 16);
}
__device__ __forceinline__ float b2f(u16 u) { return __uint_as_float(((u32)u) << 16); }

// fragment-packed index for element (r, k), K-dim = 512
__device__ __forceinline__ size_t pidx(int r, int k) {
  return (size_t)(((r >> 4) * 16 + (k >> 5)) * 512 + ((k >> 3) & 3) * 128 + (r & 15) * 8 + (k & 7));
}

__device__ __forceinline__ void gll16(const void* g, void* l) {
  __builtin_amdgcn_global_load_lds((__attribute__((address_space(1))) void*)(void*)g,
                                   (__attribute__((address_space(3))) void*)l, 16, 0, 0);
}

// ---- prep job b in [0,80): pack K into slot0 (4 forms); split z0 -> U_0 hi/lo ----
__device__ void prep_job(int b, int tid, const float* __restrict__ Kc,
                         const float* __restrict__ z0, u16* __restrict__ P,
                         u16* __restrict__ Uh, u16* __restrict__ Ul) {
  if (b < 64) {
    int r0 = (b >> 3) * 64, c0b = (b & 7) * 64;
#pragma unroll
    for (int q = 0; q < 2; ++q) {
      int g = q * 256 + tid;            // 512 groups: 64 rows x 8 col-groups
      int r = r0 + (g >> 3), c0 = c0b + (g & 7) * 8;
      float4 v0 = *(const float4*)(Kc + (size_t)r * 512 + c0);
      float4 v1 = *(const float4*)(Kc + (size_t)r * 512 + c0 + 4);
      float v[8] = {v0.x, v0.y, v0.z, v0.w, v1.x, v1.y, v1.z, v1.w};
      u16x8 h8, l8v;
#pragma unroll
      for (int j = 0; j < 8; ++j) {
        u16 h = f2b(v[j]);
        h8[j] = h;
        l8v[j] = f2b(v[j] - b2f(h));
        size_t ib = pidx(c0 + j, r);    // transposed form, scalar
        P[2 * MAT + ib] = h;
        P[3 * MAT + ib] = l8v[j];
      }
      size_t ia = pidx(r, c0);          // row form, contiguous 8 -> 16B stores
      *(u16x8*)(P + ia) = h8;
      *(u16x8*)(P + MAT + ia) = l8v;
    }
  } else {
    int idb = b - 64;  // 16 jobs x 4 iters x 256 threads x 8 elems = 131072
#pragma unroll
    for (int q = 0; q < 4; ++q) {
      int g = (idb * 4 + q) * 256 + tid;
      int r = g >> 6, c0 = (g & 63) * 8;
      float4 v0 = *(const float4*)(z0 + (size_t)r * 512 + c0);
      float4 v1 = *(const float4*)(z0 + (size_t)r * 512 + c0 + 4);
      float v[8] = {v0.x, v0.y, v0.z, v0.w, v1.x, v1.y, v1.z, v1.w};
      u16x8 h8, l8v;
#pragma unroll
      for (int j = 0; j < 8; ++j) {
        u16 h = f2b(v[j]);
        h8[j] = h;
        l8v[j] = f2b(v[j] - b2f(h));
      }
      size_t ia = pidx(r, c0);
      *(u16x8*)(Uh + ia) = h8;
      *(u16x8*)(Ul + ia) = l8v;
    }
  }
}

// ladder stage parameters (P slots: 0..15 = K^1..16; 16 = K^32; 17 = K^64; 18 = K^128)
struct LP { int asl, astrf, csl, cstrf, bsl, nfull, rm, tm, uoff, ny; };
__device__ const LP g_lp[8] = {
    {0, 0, 1, 0, 0, 1, 0x1, 0x1, 0, 8},      // s1: K^2
    {0, 1, 2, 1, 1, 1, 0x3, 0x2, 0, 8},      // s2: K^3,K^4
    {0, 1, 4, 1, 3, 1, 0xF, 0x8, 0, 8},      // s3: K^5..8
    {0, 1, 8, 1, 7, 1, 0x80, 0x80, 0, 8},    // s4: K^9..16
    {15, 0, 16, 0, 15, 1, 0x1, 0x1, 1, 12},  // s5: K^32 + U_1
    {16, 0, 17, 0, 16, 1, 0x1, 0x1, 2, 16},  // s6: K^64 + U_{2,3}
    {17, 0, 18, 0, 17, 1, 0x0, 0x1, 4, 24},  // s7: K^128 + U_{4..7}
    {18, 0, 18, 0, 18, 0, 0x0, 0x0, 8, 32},  // s8: U_{8..15}
};

// ---- ladder job: one shared B panel (hi+lo, 64KB LDS, ONE barrier). bf16x3.
__device__ void stage_job(u16* Bs, int tid, int x, int y, int z, const LP& p,
                          u16* __restrict__ P, u16* __restrict__ Uh,
                          u16* __restrict__ Ul) {
  const u16* fA = P + (size_t)p.asl * SLOT;
  u16* fC = P + (size_t)p.csl * SLOT;
  const u16* Bh = P + (size_t)p.bsl * SLOT + 2 * MAT;
  const u16 *Ah, *Al;
  u16 *Ch, *Clo, *CTh, *CTl;
  int m0;
  bool full = (y < 8 * p.nfull);
  bool wrow, wtlo;
  if (full) {
    Ah = fA + (size_t)z * (p.astrf ? SLOT : 0);
    Al = Ah + MAT;
    Ch = fC + (size_t)z * (p.cstrf ? SLOT : 0);
    Clo = Ch + MAT;
    CTh = Ch + 2 * MAT;
    CTl = Ch + 3 * MAT;
    m0 = y * 64;
    wrow = (p.rm >> z) & 1;
    wtlo = (p.tm >> z) & 1;
  } else {
    int yy = y - 8 * p.nfull;
    int u = yy >> 2;
    Ah = Uh + (size_t)u * WSLOT;
    Al = Ah + 16 * (size_t)WSLOT;
    Ch = Uh + (size_t)(p.uoff + u) * WSLOT;
    Clo = Ch + 16 * (size_t)WSLOT;
    CTh = CTl = nullptr;
    m0 = (yy & 3) * 64;
    wrow = true;
    wtlo = false;
  }
  const u16* Bl = Bh + MAT;
  int n0 = x * 32;
  int wv = tid >> 6, lane = tid & 63;
  int mrow = lane & 15, quad = lane >> 4;
  int l8 = lane * 8;
  int nchunk0 = n0 >> 4;                 // 2 nchunks x 16 kchunks = 32 chunks/form
  const u16* ph = Bh + (size_t)nchunk0 * 16 * 512;  // contiguous 32KB panel
  const u16* pl = Bl + (size_t)nchunk0 * 16 * 512;
#pragma unroll
  for (int i = 0; i < 8; ++i) {          // wave wv stages chunks wv*8+i (hi & lo)
    int ch = wv * 8 + i;
    gll16(ph + (size_t)ch * 512 + l8, Bs + ch * 512);
    gll16(pl + (size_t)ch * 512 + l8, Bs + 16384 + ch * 512);
  }
  __syncthreads();                       // the ONLY barrier in the K-loop
  int mc = (m0 >> 4) + wv;               // wave-tile 16x32 (4-way m-split)
  f32x4 acc[2] = {};
#pragma unroll 4
  for (int kt = 0; kt < 16; ++kt) {
    size_t co = (size_t)(mc * 16 + kt) * 512 + l8;
    bf16x8 ah = *(const bf16x8*)(Ah + co);
    bf16x8 al = *(const bf16x8*)(Al + co);
#pragma unroll
    for (int nt = 0; nt < 2; ++nt) {
      bf16x8 bh = *(const bf16x8*)(Bs + (nt * 16 + kt) * 512 + l8);
      bf16x8 bl = *(const bf16x8*)(Bs + 16384 + (nt * 16 + kt) * 512 + l8);
      acc[nt] = __builtin_amdgcn_mfma_f32_16x16x32_bf16(ah, bh, acc[nt], 0, 0, 0);
      acc[nt] = __builtin_amdgcn_mfma_f32_16x16x32_bf16(al, bh, acc[nt], 0, 0, 0);
      acc[nt] = __builtin_amdgcn_mfma_f32_16x16x32_bf16(ah, bl, acc[nt], 0, 0, 0);
    }
  }
  // C/D layout: col = lane&15, row = quad*4 + reg
  int mbase = m0 + wv * 16 + quad * 4;
#pragma unroll
  for (int nt = 0; nt < 2; ++nt) {
    int n = n0 + nt * 16 + mrow;
    u16x4 h4, l4;
#pragma unroll
    for (int r = 0; r < 4; ++r) {
      float v = acc[nt][r];
      u16 h = f2b(v);
      h4[r] = h;
      l4[r] = f2b(v - b2f(h));
    }
    if (wrow) {
#pragma unroll
      for (int r = 0; r < 4; ++r) {
        size_t ia = pidx(mbase + r, n);
        Ch[ia] = h4[r];
        Clo[ia] = l4[r];
      }
    }
    if (full) {
      size_t ib = pidx(n, mbase);        // 4 consecutive u16 (m&7 = quad&1*4 + r)
      *(u16x4*)(CTh + ib) = h4;
      if (wtlo) *(u16x4*)(CTl + ib) = l4;
    }
  }
}

// ---- out job: out[:, zo, :] = U_{zo>>4} @ K^{(zo&15)+1}, plain bf16.
// 256x64 tile, whole-K 64KB panel staged once, ONE barrier, 4-way m-split.
__device__ void out_job(u16* Bs, int tid, int x, int zo,
                        const u16* __restrict__ Ub, const u16* __restrict__ PT0,
                        float* __restrict__ out) {
  const u16* A = Ub + (size_t)(zo >> 4) * WSLOT;
  const u16* Bt = PT0 + (size_t)(zo & 15) * SLOT;
  int n0 = x * 64;
  int wv = tid >> 6, lane = tid & 63;
  int mrow = lane & 15, quad = lane >> 4;
  int l8 = lane * 8;
  const u16* pb = Bt + (size_t)(n0 >> 4) * 16 * 512;  // contiguous 64KB panel
#pragma unroll
  for (int i = 0; i < 16; ++i) {
    int ch = wv * 16 + i;
    gll16(pb + (size_t)ch * 512 + l8, Bs + ch * 512);
  }
  __syncthreads();
  int mc0 = wv * 4;                      // wave-tile 64x64
  f32x4 acc[4][4] = {};
#pragma unroll 4
  for (int kt = 0; kt < 16; ++kt) {
    bf16x8 a[4], b[4];
#pragma unroll
    for (int mt = 0; mt < 4; ++mt)
      a[mt] = *(const bf16x8*)(A + (size_t)((mc0 + mt) * 16 + kt) * 512 + l8);
#pragma unroll
    for (int nt = 0; nt < 4; ++nt)
      b[nt] = *(const bf16x8*)(Bs + (nt * 16 + kt) * 512 + l8);
#pragma unroll
    for (int mt = 0; mt < 4; ++mt)
#pragma unroll
      for (int nt = 0; nt < 4; ++nt)
        acc[mt][nt] = __builtin_amdgcn_mfma_f32_16x16x32_bf16(a[mt], b[nt], acc[mt][nt], 0, 0, 0);
  }
#pragma unroll
  for (int mt = 0; mt < 4; ++mt)
#pragma unroll
    for (int nt = 0; nt < 4; ++nt) {
      int gb = wv * 64 + mt * 16 + quad * 4;
      int gd = n0 + nt * 16 + mrow;
#pragma unroll
      for (int r = 0; r < 4; ++r)
        out[((size_t)(gb + r) * 256 + zo) * 512 + gd] = acc[mt][nt][r];
    }
}

// ---- job ranges in ticket order. kind: 0=prep, 1=ladder (prm=stage),
// 2=out (prm=zbase). dep/sig index stage counters ctrl[CPAD*(1+i)]:
// 0=prep(80) 1=s1(128) 2=s2(256) 3=s3(512) 4=s4(1024) 5=s5(192) 6=s6(256)
// 7=s7(384) 8=s8(512). Every range depends only on earlier ranges -> live.
struct RG { int start, kind, prm, dep, need, sig; };
__device__ const RG g_rg[18] = {
    {0,    0, 0,  -1, 0,    0},   // prep
    {80,   1, 0,   0, 80,   1},   // s1
    {208,  2, 0,   0, 80,  -1},   // out z=0
    {216,  1, 1,   1, 128,  2},   // s2
    {472,  2, 1,   1, 128, -1},   // out z=1
    {480,  1, 2,   2, 256,  3},   // s3
    {992,  2, 2,   2, 256, -1},   // out z=2..3
    {1008, 1, 3,   3, 512,  4},   // s4
    {2032, 2, 4,   3, 512, -1},   // out z=4..7
    {2064, 1, 4,   4, 1024, 5},   // s5
    {2256, 2, 8,   4, 1024,-1},   // out z=8..15
    {2320, 1, 5,   5, 192,  6},   // s6
    {2576, 2, 16,  5, 192, -1},   // out z=16..31
    {2704, 1, 6,   6, 256,  7},   // s7
    {3088, 2, 32,  6, 256, -1},   // out z=32..63
    {3344, 1, 7,   7, 384,  8},   // s8
    {3856, 2, 64,  7, 384, -1},   // out z=64..127
    {4368, 2, 128, 8, 512, -1},   // out z=128..255
};

__global__ __launch_bounds__(256, 2) void mega(const float* Kc, const float* z0,
                                               u16* P, u16* Uh, u16* Ul,
                                               float* out, u32* ctrl) {
  __shared__ u16 Bs[32768];  // 64KB
  __shared__ int sh_t;
  int tid = threadIdx.x;
  for (;;) {
    __syncthreads();                     // all threads done with prior job/sh_t
    if (tid == 0)
      sh_t = (int)__hip_atomic_fetch_add(ctrl, 1u, __ATOMIC_RELAXED,
                                         __HIP_MEMORY_SCOPE_AGENT);
    __syncthreads();
    int t = sh_t;
    if (t >= NJOBS) return;
    int ri = 0;
#pragma unroll
    for (int i = 1; i < 18; ++i)
      if (t >= g_rg[i].start) ri = i;
    RG rg = g_rg[ri];
    if (rg.dep >= 0) {
      if (tid == 0) {
        u32* c = ctrl + CPAD * (1 + rg.dep);
        if ((int)__hip_atomic_load(c, __ATOMIC_RELAXED, __HIP_MEMORY_SCOPE_AGENT) < rg.need) {
          do {
            __builtin_amdgcn_s_sleep(16);  // ~1us backoff: pollers are cheap
          } while ((int)__hip_atomic_load(c, __ATOMIC_RELAXED, __HIP_MEMORY_SCOPE_AGENT) < rg.need);
        }
        __threadfence();                 // acquire: invalidate stale caches
      }
      __syncthreads();
    }
    int e = t - rg.start;
    if (rg.kind == 0) {
      prep_job(e, tid, Kc, z0, P, Uh, Ul);
    } else if (rg.kind == 1) {
      LP p = g_lp[rg.prm];
      int x = e & 15, q = e >> 4;
      stage_job(Bs, tid, x, q % p.ny, q / p.ny, p, P, Uh, Ul);
    } else {
      out_job(Bs, tid, e & 7, rg.prm + (e >> 3), Uh, P + 2 * MAT, out);
    }
    __syncthreads();                     // drain block's stores (vmcnt 0)
    if (rg.sig >= 0 && tid == 0) {
      __threadfence();                   // release: writeback before signal
      __hip_atomic_fetch_add(ctrl + CPAD * (1 + rg.sig), 1u, __ATOMIC_RELAXED,
                             __HIP_MEMORY_SCOPE_AGENT);
    }
  }
}

extern "C" void kernel_launch(void* const* d_in, const int* in_sizes, int n_in,
                              void* d_out, int out_size, void* d_ws, size_t ws_size,
                              hipStream_t stream) {
  const float* z0 = (const float*)d_in[0];
  const float* Kc = (const float*)d_in[1];
  float* out = (float*)d_out;
  // ws layout (u16): Uh[16*WSLOT] | Ul[16*WSLOT] | P[19*SLOT]
  // P slots: 0..15 = K^1..K^16; 16 = K^32; 17 = K^64; 18 = K^128
  u16* Uh = (u16*)d_ws;
  u16* Ul = Uh + 16 * (size_t)WSLOT;
  u16* P = Ul + 16 * (size_t)WSLOT;
  // control block (ticket + 9 padded stage counters) lives in a DEAD hole:
  // slot 8's row-hi form (K^9 rows) is never written nor read.
  u32* ctrl = (u32*)(P + 8 * (size_t)SLOT);

  hipMemsetAsync(ctrl, 0, CPAD * 4 * 16, stream);
  mega<<<dim3(512), dim3(256), 0, stream>>>(Kc, z0, P, Uh, Ul, out, ctrl);
}